// Round 6
// baseline (460.247 us; speedup 1.0000x reference)
//
#include <hip/hip_runtime.h>
#include <stdint.h>

// ---------- bf16 helpers (storage = unsigned short) ----------
__device__ __forceinline__ float b2f(unsigned short u) {
    union { uint32_t i; float f; } v; v.i = ((uint32_t)u) << 16; return v.f;
}
__device__ __forceinline__ unsigned short f2b(float f) {
    union { float f; uint32_t i; } v; v.f = f;
    uint32_t r = v.i + 0x7fffu + ((v.i >> 16) & 1u);   // RNE
    return (unsigned short)(r >> 16);
}

typedef __bf16 bf16x8 __attribute__((ext_vector_type(8)));
typedef float  f32x16 __attribute__((ext_vector_type(16)));

// ---------------------------------------------------------------------------
// build_T body: T[rm=(r1*16+n2)*16+m2][n3][m3] = sum_r2 c1[rm][r2]*c2[...]
// 524288 elems per layer (2048 blocks x 256 each; R3 lesson: never shrink).
// ---------------------------------------------------------------------------
template<int N3, int M3>
__device__ __forceinline__ void build_T_body(int e,
                                             const float* __restrict__ c1,
                                             const float* __restrict__ c2,
                                             float* __restrict__ T) {
    int m3 = e % M3;
    int t  = e / M3;
    int n3 = t % N3;
    int rm = t / N3;
    float s = 0.f;
#pragma unroll
    for (int r2 = 0; r2 < 16; ++r2)
        s += c1[rm * 16 + r2] * c2[(r2 * N3 + n3) * M3 + m3];
    T[e] = s;
}

// Fused stage-1 kernel: blocks [0,2048) -> T1, [2048,4096) -> T2,
// [4096,6144) -> cvt x (f32) -> xb (bf16), 8 elems/thread.
__global__ __launch_bounds__(256)
void prep_stage1(const float* __restrict__ c11, const float* __restrict__ c12,
                 float* __restrict__ T1,
                 const float* __restrict__ c21, const float* __restrict__ c22,
                 float* __restrict__ T2,
                 const float* __restrict__ x, unsigned short* __restrict__ xb) {
    const int b = blockIdx.x;
    if (b < 2048) {
        build_T_body<8, 16>(b * 256 + threadIdx.x, c11, c12, T1);
    } else if (b < 4096) {
        build_T_body<16, 8>((b - 2048) * 256 + threadIdx.x, c21, c22, T2);
    } else {
        const int t = (b - 4096) * 256 + threadIdx.x;
        const float4* p = (const float4*)(x + (size_t)t * 8);
        float4 f0 = p[0], f1 = p[1];
        int4 o;
        o.x = (uint32_t)f2b(f0.x) | ((uint32_t)f2b(f0.y) << 16);
        o.y = (uint32_t)f2b(f0.z) | ((uint32_t)f2b(f0.w) << 16);
        o.z = (uint32_t)f2b(f1.x) | ((uint32_t)f2b(f1.y) << 16);
        o.w = (uint32_t)f2b(f1.z) | ((uint32_t)f2b(f1.w) << 16);
        ((int4*)xb)[t] = o;
    }
}

// ---------------------------------------------------------------------------
// build_W body: thread t = (((n1*M1+m1)*N2+n2)*M2+m2)*M3+m3.
// W[outRow=(m1*M2+m2)*M3+m3][K] (B^T layout, bf16), K = N1*N2*N3.
// ---------------------------------------------------------------------------
template<int N1, int N2, int N3, int M1, int M2, int M3>
__device__ __forceinline__ void build_W_body(int t,
                                             const float* __restrict__ c0,
                                             const float* __restrict__ T,
                                             unsigned short* __restrict__ W) {
    constexpr int K = N1 * N2 * N3;
    int m3 = t % M3;
    int m2 = (t / M3) % M2;
    int n2 = (t / (M3 * M2)) % N2;
    int m1 = (t / (M3 * M2 * N2)) % M1;
    int n1 =  t / (M3 * M2 * N2 * M1);

    float c0r[16];
    const float4* c0p = (const float4*)(c0 + (n1 * M1 + m1) * 16);
#pragma unroll
    for (int i = 0; i < 4; ++i) ((float4*)c0r)[i] = c0p[i];

    float acc[N3] = {};
#pragma unroll
    for (int r1 = 0; r1 < 16; ++r1) {
        const float* Tp = T + (size_t)(((r1 * 16 + n2) * 16 + m2) * N3) * M3 + m3;
#pragma unroll
        for (int n3 = 0; n3 < N3; ++n3)
            acc[n3] += c0r[r1] * Tp[n3 * M3];
    }

    unsigned short ob[N3];
#pragma unroll
    for (int n3 = 0; n3 < N3; ++n3) ob[n3] = f2b(acc[n3]);

    unsigned short* dst = W + (size_t)((m1 * M2 + m2) * M3 + m3) * K
                            + (n1 * N2 + n2) * N3;
#pragma unroll
    for (int c = 0; c < N3 / 8; ++c)
        ((int4*)dst)[c] = ((const int4*)ob)[c];
}

// Fused: blocks [0,2048) -> W1, [2048,3072) -> W2.
__global__ __launch_bounds__(256)
void build_W_both(const float* __restrict__ c10, const float* __restrict__ T1,
                  unsigned short* __restrict__ W1,
                  const float* __restrict__ c20, const float* __restrict__ T2,
                  unsigned short* __restrict__ W2) {
    const int b = blockIdx.x;
    if (b < 2048)
        build_W_body<8, 16, 8, 16, 16, 16>(b * 256 + threadIdx.x, c10, T1, W1);
    else
        build_W_body<16, 16, 16, 8, 16, 8>((b - 2048) * 256 + threadIdx.x, c20, T2, W2);
}

// Standalone (small-workspace fallback path).
template<int N1, int N2, int N3, int M1, int M2, int M3>
__global__ __launch_bounds__(256)
void build_W(const float* __restrict__ c0, const float* __restrict__ T,
             unsigned short* __restrict__ W) {
    build_W_body<N1, N2, N3, M1, M2, M3>(blockIdx.x * 256 + threadIdx.x, c0, T, W);
}

// ---------------------------------------------------------------------------
// gemm_pc4: R0's producer-consumer GEMM + RAW-BARRIER counted pipeline.
//
// C[M][Ncols] = A[M][K] * Bt[Ncols][K]^T + bias (opt GELU).  BK=64,
// 512 threads: waves 0-3 consume (2x2 grid, (BM/2)x(BN/2) each, 32x32x16
// MFMA), waves 4-7 produce (global->reg->LDS, double-buffered).
//
// THE R6 CHANGE: __syncthreads() is replaced by
//     s_waitcnt lgkmcnt(0); s_barrier;   (+ "memory"-clobber bracketing)
// __syncthreads drains vmcnt(0) before s_barrier (m97 drain) -- that wait
// on just-issued prefetch loads was R0/R5's per-tile bubble.  Producers
// only READ global memory, so barrier visibility needs lgkmcnt only; the
// prefetch loads stay IN FLIGHT across the raw s_barrier.
//
// Producer iter t: STORE(t+1) (regs loaded at iter t-1 -> compiler's
// counted vmcnt wait covers a full tile-phase in flight), then LOAD(t+2)
// (in flight across the barrier), then lgkm-drain + barrier.  ONE register
// tile set (R4 lesson: two sets -> scratch spill, 418MB phantom writes).
//
// Barrier ledger: both roles execute 1+NT barriers.  Tile t+1 stored
// between B_t and B_{t+1}; consumer reads it after B_{t+1}; its buffer is
// overwritten (tile t+3) after B_{t+2}.  Consumer drains lgkmcnt before
// each barrier so in-flight ds_reads can't cross into the producer's next
// ds_writes.
//
// LDS swizzle (R0-proven, 0 conflicts): lane jj stores global chunk
// jj^key(r) at slot jj, key(r)=(r&7)^((r>>3)&7); read slot = g^key(r).
// C/D map (m74/m101): col=lane&31, row=(reg&3)+8*(reg>>2)+4*(lane>>5).
// XCD-chunked bijective block swizzle (grid % 8 == 0).
// ---------------------------------------------------------------------------
#define PC4_SYNC                                                   \
    asm volatile("s_waitcnt lgkmcnt(0)" ::: "memory");             \
    __builtin_amdgcn_s_barrier();                                  \
    asm volatile("" ::: "memory");

template<int BM, int BN, int KTOT, int GX, bool DO_GELU, bool C_F32>
__global__ __launch_bounds__(512, 4)
void gemm_pc4(const unsigned short* __restrict__ A,
              const unsigned short* __restrict__ Bt,
              const float* __restrict__ bias,
              void* __restrict__ Cv,
              int Ncols)
{
    constexpr int BK  = 64;
    constexpr int NT  = KTOT / BK;
    constexpr int CA  = BM / 8, CB = BN / 8;   // 8-row chunks per tile
    constexpr int PA  = CA / 4, PB = CB / 4;   // chunks per producer wave
    constexpr int FI  = BM / 64, FJ = BN / 64;
    constexpr int ASZ = BM * BK, BSZ = BN * BK;
    __shared__ unsigned short As[2 * ASZ];
    __shared__ unsigned short Bs[2 * BSZ];

    const int tid   = threadIdx.x;
    const int lane  = tid & 63;
    const int wave  = tid >> 6;
    const int lr    = lane >> 3;
    const int jj    = lane & 7;
    const int m32   = lane & 31;
    const int khalf = lane >> 5;

    // XCD-chunked bijective swizzle (total % 8 == 0: 1024 / 512)
    int lin = (int)blockIdx.y * GX + (int)blockIdx.x;
    const int total = GX * (int)gridDim.y;
    lin = (lin & 7) * (total >> 3) + (lin >> 3);
    const int rowBase = (lin / GX) * BM;
    const int colBase = (lin % GX) * BN;

    if (wave >= 4) {
        // ================= PRODUCER =================
        const int pw = wave - 4;
        int4 aR[PA], bR[PB];      // ONE tile set only

#define PC4_LOAD(T_)                                                          \
        { const int kk = (T_) * BK;                                           \
          _Pragma("unroll")                                                   \
          for (int it = 0; it < PA; ++it) {                                   \
              const int c  = pw * PA + it;                                    \
              const int jg = jj ^ lr ^ (c & 7);                               \
              aR[it] = *(const int4*)(A +                                     \
                  (size_t)(rowBase + c * 8 + lr) * KTOT + kk + jg * 8);       \
          }                                                                   \
          _Pragma("unroll")                                                   \
          for (int it = 0; it < PB; ++it) {                                   \
              const int c  = pw * PB + it;                                    \
              const int jg = jj ^ lr ^ (c & 7);                               \
              bR[it] = *(const int4*)(Bt +                                    \
                  (size_t)(colBase + c * 8 + lr) * KTOT + kk + jg * 8);       \
          } }

#define PC4_STORE(B_)                                                         \
        { unsigned short* As_ = As + (B_) * ASZ;                              \
          unsigned short* Bs_ = Bs + (B_) * BSZ;                              \
          _Pragma("unroll")                                                   \
          for (int it = 0; it < PA; ++it)                                     \
              *(int4*)&As_[(pw * PA + it) * 512 + lane * 8] = aR[it];         \
          _Pragma("unroll")                                                   \
          for (int it = 0; it < PB; ++it)                                     \
              *(int4*)&Bs_[(pw * PB + it) * 512 + lane * 8] = bR[it]; }

        // prologue: stage tile 0; issue tile-1 loads (stay in flight)
        PC4_LOAD(0)
        PC4_STORE(0)
        PC4_LOAD(1)
        PC4_SYNC

        for (int t = 0; t < NT; ++t) {
            if (t + 1 < NT) PC4_STORE((t + 1) & 1)   // regs from iter t-1
            if (t + 2 < NT) PC4_LOAD(t + 2)          // in flight across bar
            PC4_SYNC
        }
#undef PC4_LOAD
#undef PC4_STORE
    } else {
        // ================= CONSUMER =================
        const int wm = wave >> 1, wn = wave & 1;
        const int waveM = wm * (BM / 2), waveN = wn * (BN / 2);
        f32x16 acc[FI][FJ] = {};

        PC4_SYNC                          // tile 0 staged

        for (int t = 0; t < NT; ++t) {
            const unsigned short* Ab = As + (t & 1) * ASZ;
            const unsigned short* Bb = Bs + (t & 1) * BSZ;
#pragma unroll
            for (int ks = 0; ks < 4; ++ks) {
                bf16x8 a_f[FI], b_f[FJ];
                const int g = ks * 2 + khalf;
#pragma unroll
                for (int i = 0; i < FI; ++i) {
                    const int r = waveM + i * 32 + m32;
                    const int key = (r & 7) ^ ((r >> 3) & 7);
                    a_f[i] = *(const bf16x8*)&Ab[r * BK + ((g ^ key) << 3)];
                }
#pragma unroll
                for (int j = 0; j < FJ; ++j) {
                    const int r = waveN + j * 32 + m32;
                    const int key = (r & 7) ^ ((r >> 3) & 7);
                    b_f[j] = *(const bf16x8*)&Bb[r * BK + ((g ^ key) << 3)];
                }
#pragma unroll
                for (int i = 0; i < FI; ++i)
#pragma unroll
                    for (int j = 0; j < FJ; ++j)
                        acc[i][j] = __builtin_amdgcn_mfma_f32_32x32x16_bf16(
                            a_f[i], b_f[j], acc[i][j], 0, 0, 0);
            }
            PC4_SYNC
        }

        // epilogue: col=lane&31, row=(reg&3)+8*(reg>>2)+4*(lane>>5)
#pragma unroll
        for (int i = 0; i < FI; ++i) {
#pragma unroll
            for (int j = 0; j < FJ; ++j) {
                const int col = colBase + waveN + j * 32 + m32;
                const float bv = bias[col];
#pragma unroll
                for (int reg = 0; reg < 16; ++reg) {
                    const int row = rowBase + waveM + i * 32 +
                                    (reg & 3) + 8 * (reg >> 2) + 4 * khalf;
                    float z = acc[i][j][reg] + bv;
                    if (DO_GELU)
                        z = 0.5f * z * (1.f + erff(z * 0.70710678118654752f));
                    const size_t off = (size_t)row * Ncols + col;
                    if (C_F32) ((float*)Cv)[off] = z;
                    else       ((unsigned short*)Cv)[off] = f2b(z);
                }
            }
        }
    }
}

// ---------------------------------------------------------------------------
extern "C" void kernel_launch(void* const* d_in, const int* in_sizes, int n_in,
                              void* d_out, int out_size, void* d_ws, size_t ws_size,
                              hipStream_t stream) {
    const float* x      = (const float*)d_in[0];   // [4096,1024] fp32
    const float* fc1_c0 = (const float*)d_in[1];
    const float* fc1_c1 = (const float*)d_in[2];
    const float* fc1_c2 = (const float*)d_in[3];
    const float* fc1_b  = (const float*)d_in[4];
    const float* fc2_c0 = (const float*)d_in[5];
    const float* fc2_c1 = (const float*)d_in[6];
    const float* fc2_c2 = (const float*)d_in[7];
    const float* fc2_b  = (const float*)d_in[8];

    // d_out (16 MB f32) as pre-GEMM2 scratch -- gemm2 overwrites all of it:
    //   T1 [0,2M), T2 [2,4M), xb bf16 [4,12M)
    float* T1 = (float*)d_out;
    float* T2 = (float*)d_out + 524288;
    unsigned short* xb = (unsigned short*)((char*)d_out + (4u << 20));

    char* ws = (char*)d_ws;
    const bool big = ws_size >= (48ull << 20);

    // K0: T1 + T2 + cvt(x->xb), fused (2048+2048+2048 blocks)
    prep_stage1<<<6144, 256, 0, stream>>>(fc1_c1, fc1_c2, T1,
                                          fc2_c1, fc2_c2, T2, x, xb);

    if (big) {
        // ws: W1 [0,8M), W2 [8,16M), h bf16 [16,48M)
        unsigned short* W1 = (unsigned short*)ws;
        unsigned short* W2 = (unsigned short*)(ws + (8u << 20));
        unsigned short* h  = (unsigned short*)(ws + (16u << 20));

        // K1: both weight matrices (2048 + 1024 blocks)
        build_W_both<<<3072, 256, 0, stream>>>(fc1_c0, T1, W1,
                                               fc2_c0, T2, W2);
        // K2: GEMM1 [4096,1024]x[1024,4096] + bias + GELU -> h (bf16)
        gemm_pc4<128, 128, 1024, 32, true, false>
            <<<dim3(32, 32), 512, 0, stream>>>(xb, W1, fc1_b, h, 4096);
        // K3: GEMM2 [4096,4096]x[4096,1024] + bias -> d_out (f32)
        //     (overwrites T1/T2/xb scratch -- all dead by now)
        gemm_pc4<128, 64, 4096, 16, false, true>
            <<<dim3(16, 32), 512, 0, stream>>>(h, W2, fc2_b, d_out, 1024);
    } else {
        // Fallback (ws >= 40 MB): W [0,8M) reused per layer, h [8,40M).
        unsigned short* W = (unsigned short*)ws;
        unsigned short* h = (unsigned short*)(ws + (8u << 20));

        build_W<8, 16, 8, 16, 16, 16><<<2048, 256, 0, stream>>>(fc1_c0, T1, W);
        gemm_pc4<128, 128, 1024, 32, true, false>
            <<<dim3(32, 32), 512, 0, stream>>>(xb, W, fc1_b, h, 4096);
        build_W<16, 16, 16, 8, 16, 8><<<1024, 256, 0, stream>>>(fc2_c0, T2, W);
        gemm_pc4<128, 64, 4096, 16, false, true>
            <<<dim3(16, 32), 512, 0, stream>>>(h, W, fc2_b, d_out, 1024);
    }
}

// Round 7
// 217.430 us; speedup vs baseline: 2.1168x; 2.1168x over previous
//
#include <hip/hip_runtime.h>
#include <stdint.h>

// ---------- bf16 helpers (storage = unsigned short) ----------
__device__ __forceinline__ float b2f(unsigned short u) {
    union { uint32_t i; float f; } v; v.i = ((uint32_t)u) << 16; return v.f;
}
__device__ __forceinline__ unsigned short f2b(float f) {
    union { float f; uint32_t i; } v; v.f = f;
    uint32_t r = v.i + 0x7fffu + ((v.i >> 16) & 1u);   // RNE
    return (unsigned short)(r >> 16);
}

typedef __bf16 bf16x8 __attribute__((ext_vector_type(8)));
typedef float  f32x16 __attribute__((ext_vector_type(16)));

// ---------------------------------------------------------------------------
// build_T body: T[rm=(r1*16+n2)*16+m2][n3][m3] = sum_r2 c1[rm][r2]*c2[...]
// 524288 elems per layer (2048 blocks x 256; R3 lesson: never shrink).
// ---------------------------------------------------------------------------
template<int N3, int M3>
__device__ __forceinline__ void build_T_body(int e,
                                             const float* __restrict__ c1,
                                             const float* __restrict__ c2,
                                             float* __restrict__ T) {
    int m3 = e % M3;
    int t  = e / M3;
    int n3 = t % N3;
    int rm = t / N3;
    float s = 0.f;
#pragma unroll
    for (int r2 = 0; r2 < 16; ++r2)
        s += c1[rm * 16 + r2] * c2[(r2 * N3 + n3) * M3 + m3];
    T[e] = s;
}

// Fused stage-1: blocks [0,2048) -> T1, [2048,4096) -> T2,
// [4096,6144) -> cvt x (f32) -> xb (bf16), 8 elems/thread.
// Verified passing in R5/R6.
__global__ __launch_bounds__(256)
void prep_stage1(const float* __restrict__ c11, const float* __restrict__ c12,
                 float* __restrict__ T1,
                 const float* __restrict__ c21, const float* __restrict__ c22,
                 float* __restrict__ T2,
                 const float* __restrict__ x, unsigned short* __restrict__ xb) {
    const int b = blockIdx.x;
    if (b < 2048) {
        build_T_body<8, 16>(b * 256 + threadIdx.x, c11, c12, T1);
    } else if (b < 4096) {
        build_T_body<16, 8>((b - 2048) * 256 + threadIdx.x, c21, c22, T2);
    } else {
        const int t = (b - 4096) * 256 + threadIdx.x;
        const float4* p = (const float4*)(x + (size_t)t * 8);
        float4 f0 = p[0], f1 = p[1];
        int4 o;
        o.x = (uint32_t)f2b(f0.x) | ((uint32_t)f2b(f0.y) << 16);
        o.y = (uint32_t)f2b(f0.z) | ((uint32_t)f2b(f0.w) << 16);
        o.z = (uint32_t)f2b(f1.x) | ((uint32_t)f2b(f1.y) << 16);
        o.w = (uint32_t)f2b(f1.z) | ((uint32_t)f2b(f1.w) << 16);
        ((int4*)xb)[t] = o;
    }
}

// ---------------------------------------------------------------------------
// build_W body: thread t = (((n1*M1+m1)*N2+n2)*M2+m2)*M3+m3.
// W[outRow=(m1*M2+m2)*M3+m3][K] (B^T layout, bf16), K = N1*N2*N3.
// ---------------------------------------------------------------------------
template<int N1, int N2, int N3, int M1, int M2, int M3>
__device__ __forceinline__ void build_W_body(int t,
                                             const float* __restrict__ c0,
                                             const float* __restrict__ T,
                                             unsigned short* __restrict__ W) {
    constexpr int K = N1 * N2 * N3;
    int m3 = t % M3;
    int m2 = (t / M3) % M2;
    int n2 = (t / (M3 * M2)) % N2;
    int m1 = (t / (M3 * M2 * N2)) % M1;
    int n1 =  t / (M3 * M2 * N2 * M1);

    float c0r[16];
    const float4* c0p = (const float4*)(c0 + (n1 * M1 + m1) * 16);
#pragma unroll
    for (int i = 0; i < 4; ++i) ((float4*)c0r)[i] = c0p[i];

    float acc[N3] = {};
#pragma unroll
    for (int r1 = 0; r1 < 16; ++r1) {
        const float* Tp = T + (size_t)(((r1 * 16 + n2) * 16 + m2) * N3) * M3 + m3;
#pragma unroll
        for (int n3 = 0; n3 < N3; ++n3)
            acc[n3] += c0r[r1] * Tp[n3 * M3];
    }

    unsigned short ob[N3];
#pragma unroll
    for (int n3 = 0; n3 < N3; ++n3) ob[n3] = f2b(acc[n3]);

    unsigned short* dst = W + (size_t)((m1 * M2 + m2) * M3 + m3) * K
                            + (n1 * N2 + n2) * N3;
#pragma unroll
    for (int c = 0; c < N3 / 8; ++c)
        ((int4*)dst)[c] = ((const int4*)ob)[c];
}

// Fused: blocks [0,2048) -> W1, [2048,3072) -> W2.  Verified R5/R6.
__global__ __launch_bounds__(256)
void build_W_both(const float* __restrict__ c10, const float* __restrict__ T1,
                  unsigned short* __restrict__ W1,
                  const float* __restrict__ c20, const float* __restrict__ T2,
                  unsigned short* __restrict__ W2) {
    const int b = blockIdx.x;
    if (b < 2048)
        build_W_body<8, 16, 8, 16, 16, 16>(b * 256 + threadIdx.x, c10, T1, W1);
    else
        build_W_body<16, 16, 16, 8, 16, 8>((b - 2048) * 256 + threadIdx.x, c20, T2, W2);
}

// Standalone (small-workspace fallback path only).
template<int N1, int N2, int N3, int M1, int M2, int M3>
__global__ __launch_bounds__(256)
void build_W(const float* __restrict__ c0, const float* __restrict__ T,
             unsigned short* __restrict__ W) {
    build_W_body<N1, N2, N3, M1, M2, M3>(blockIdx.x * 256 + threadIdx.x, c0, T, W);
}

// ---------------------------------------------------------------------------
// gemm_pc: R0's producer-consumer GEMM, VERBATIM (62 us/GEMM measured, 0 bank
// conflicts, clean HBM traffic, VGPR 52).  C[M][N] = A*Bt^T + bias, opt GELU.
// 512 threads: waves 0-3 CONSUME (2x2 wave grid, (BM/2)x(BN/2) each,
// 32x32x16 MFMA), waves 4-7 PRODUCE (global->reg->LDS, double-buffered).
// One __syncthreads per K-iter; consumers never wait on vmcnt; producers
// absorb load latency during consumer MFMA.
// LDS swizzle: store slot jj holds global chunk jj^lr^(c&7);
//   read slot = (ks*2+khalf) ^ (r&7) ^ ((r>>3)&7).
// C/D mapping (m74/m101): col=lane&31, row=(reg&3)+8*(reg>>2)+4*(lane>>5).
// DO NOT restructure: rotated producers (R5), raw barriers (R6), all-wave
// rings (R2), lockstep phases (R1) all measured WORSE (82-209 us/GEMM).
// ---------------------------------------------------------------------------
#define PC_COMPUTE(BUF)                                                       \
    {                                                                         \
        _Pragma("unroll")                                                     \
        for (int ks = 0; ks < 4; ++ks) {                                      \
            bf16x8 a_f[FI], b_f[FJ];                                          \
            _Pragma("unroll")                                                 \
            for (int i = 0; i < FI; ++i) {                                    \
                const int key = (m32 & 7) ^                                   \
                    (((waveM >> 3) + 4 * i + (m32 >> 3)) & 7);                \
                const int slot = ((ks * 2 + khalf) ^ key) * 8;                \
                a_f[i] = *(const bf16x8*)&As[(BUF) * ASZ +                    \
                          (waveM + i * 32 + m32) * BK + slot];                \
            }                                                                 \
            _Pragma("unroll")                                                 \
            for (int j = 0; j < FJ; ++j) {                                    \
                const int key = (m32 & 7) ^                                   \
                    (((waveN >> 3) + 4 * j + (m32 >> 3)) & 7);                \
                const int slot = ((ks * 2 + khalf) ^ key) * 8;                \
                b_f[j] = *(const bf16x8*)&Bs[(BUF) * BSZ +                    \
                          (waveN + j * 32 + m32) * BK + slot];                \
            }                                                                 \
            _Pragma("unroll")                                                 \
            for (int i = 0; i < FI; ++i)                                      \
                _Pragma("unroll")                                             \
                for (int j = 0; j < FJ; ++j)                                  \
                    acc[i][j] = __builtin_amdgcn_mfma_f32_32x32x16_bf16(      \
                        a_f[i], b_f[j], acc[i][j], 0, 0, 0);                  \
        }                                                                     \
    }

template<int BM, int BN, int KTOT, bool DO_GELU, bool A_F32, bool C_F32>
__global__ __launch_bounds__(512, 4)
void gemm_pc(const void* __restrict__ Av,
             const unsigned short* __restrict__ Bt,
             const float* __restrict__ bias,
             void* __restrict__ Cv,
             int Ncols) {
    constexpr int BK  = 64;
    constexpr int CA  = BM / 8;
    constexpr int CB  = BN / 8;
    constexpr int PA  = CA / 4;
    constexpr int PB  = CB / 4;
    constexpr int FI  = BM / 64;
    constexpr int FJ  = BN / 64;
    constexpr int ASZ = BM * BK;
    constexpr int BSZ = BN * BK;
    __shared__ unsigned short As[2 * ASZ];
    __shared__ unsigned short Bs[2 * BSZ];

    const int tid  = threadIdx.x;
    const int lane = tid & 63;
    const int wave = tid >> 6;
    const int rowBase = blockIdx.y * BM;
    const int colBase = blockIdx.x * BN;

    const int lr    = lane >> 3;
    const int jj    = lane & 7;
    const int m32   = lane & 31;
    const int khalf = lane >> 5;

    if (wave >= 4) {
        // ================= PRODUCER =================
        const int pw = wave - 4;

        // ---- stage tile 0 -> buffer 0
#pragma unroll
        for (int it = 0; it < PA; ++it) {
            const int c  = pw * PA + it;
            const int jg = jj ^ lr ^ (c & 7);
            const size_t aoff = (size_t)(rowBase + c * 8 + lr) * KTOT + jg * 8;
            int4 v;
            if (A_F32) {
                const float* ga = (const float*)Av + aoff;
                float4 f0 = *(const float4*)ga;
                float4 f1 = *(const float4*)(ga + 4);
                v.x = (uint32_t)f2b(f0.x) | ((uint32_t)f2b(f0.y) << 16);
                v.y = (uint32_t)f2b(f0.z) | ((uint32_t)f2b(f0.w) << 16);
                v.z = (uint32_t)f2b(f1.x) | ((uint32_t)f2b(f1.y) << 16);
                v.w = (uint32_t)f2b(f1.z) | ((uint32_t)f2b(f1.w) << 16);
            } else {
                v = *(const int4*)((const unsigned short*)Av + aoff);
            }
            *(int4*)&As[c * 512 + lane * 8] = v;
        }
#pragma unroll
        for (int it = 0; it < PB; ++it) {
            const int c  = pw * PB + it;
            const int jg = jj ^ lr ^ (c & 7);
            *(int4*)&Bs[c * 512 + lane * 8] =
                *(const int4*)(Bt + (size_t)(colBase + c * 8 + lr) * KTOT + jg * 8);
        }
        __syncthreads();

        int buf = 1;
        for (int k0 = BK; k0 < KTOT; k0 += BK) {
            int4 aR[PA], bR[PB];
#pragma unroll
            for (int it = 0; it < PA; ++it) {
                const int c  = pw * PA + it;
                const int jg = jj ^ lr ^ (c & 7);
                const size_t aoff = (size_t)(rowBase + c * 8 + lr) * KTOT + k0 + jg * 8;
                if (A_F32) {
                    const float* ga = (const float*)Av + aoff;
                    float4 f0 = *(const float4*)ga;
                    float4 f1 = *(const float4*)(ga + 4);
                    int4 v;
                    v.x = (uint32_t)f2b(f0.x) | ((uint32_t)f2b(f0.y) << 16);
                    v.y = (uint32_t)f2b(f0.z) | ((uint32_t)f2b(f0.w) << 16);
                    v.z = (uint32_t)f2b(f1.x) | ((uint32_t)f2b(f1.y) << 16);
                    v.w = (uint32_t)f2b(f1.z) | ((uint32_t)f2b(f1.w) << 16);
                    aR[it] = v;
                } else {
                    aR[it] = *(const int4*)((const unsigned short*)Av + aoff);
                }
            }
#pragma unroll
            for (int it = 0; it < PB; ++it) {
                const int c  = pw * PB + it;
                const int jg = jj ^ lr ^ (c & 7);
                bR[it] = *(const int4*)(Bt + (size_t)(colBase + c * 8 + lr) * KTOT + k0 + jg * 8);
            }
#pragma unroll
            for (int it = 0; it < PA; ++it) {
                const int c = pw * PA + it;
                *(int4*)&As[buf * ASZ + c * 512 + lane * 8] = aR[it];
            }
#pragma unroll
            for (int it = 0; it < PB; ++it) {
                const int c = pw * PB + it;
                *(int4*)&Bs[buf * BSZ + c * 512 + lane * 8] = bR[it];
            }
            __syncthreads();
            buf ^= 1;
        }
    } else {
        // ================= CONSUMER =================
        const int waveM = (wave >> 1) * (BM / 2);
        const int waveN = (wave & 1) * (BN / 2);
        f32x16 acc[FI][FJ] = {};

        __syncthreads();                 // wait for tile 0

        int cur = 0;
        for (int k0 = BK; k0 < KTOT; k0 += BK) {
            PC_COMPUTE(cur)
            __syncthreads();
            cur ^= 1;
        }
        PC_COMPUTE(cur)

        // Epilogue: col=lane&31, row=(reg&3)+8*(reg>>2)+4*khalf
#pragma unroll
        for (int i = 0; i < FI; ++i) {
#pragma unroll
            for (int j = 0; j < FJ; ++j) {
                const int col = colBase + waveN + j * 32 + m32;
                const float bv = bias[col];
#pragma unroll
                for (int reg = 0; reg < 16; ++reg) {
                    const int row = rowBase + waveM + i * 32 +
                                    (reg & 3) + 8 * (reg >> 2) + 4 * khalf;
                    float z = acc[i][j][reg] + bv;
                    if (DO_GELU)
                        z = 0.5f * z * (1.f + erff(z * 0.70710678118654752f));
                    const size_t off = (size_t)row * Ncols + col;
                    if (C_F32) ((float*)Cv)[off] = z;
                    else       ((unsigned short*)Cv)[off] = f2b(z);
                }
            }
        }
    }
}

// ---------------------------------------------------------------------------
extern "C" void kernel_launch(void* const* d_in, const int* in_sizes, int n_in,
                              void* d_out, int out_size, void* d_ws, size_t ws_size,
                              hipStream_t stream) {
    const float* x      = (const float*)d_in[0];   // [4096,1024] fp32
    const float* fc1_c0 = (const float*)d_in[1];
    const float* fc1_c1 = (const float*)d_in[2];
    const float* fc1_c2 = (const float*)d_in[3];
    const float* fc1_b  = (const float*)d_in[4];
    const float* fc2_c0 = (const float*)d_in[5];
    const float* fc2_c1 = (const float*)d_in[6];
    const float* fc2_c2 = (const float*)d_in[7];
    const float* fc2_b  = (const float*)d_in[8];

    // d_out (16 MB f32) as pre-GEMM2 scratch -- GEMM2 overwrites all of it:
    //   T1 [0,2M), T2 [2,4M), xb bf16 [4,12M).  Verified safe in R5/R6.
    float* T1 = (float*)d_out;
    float* T2 = (float*)d_out + 524288;
    unsigned short* xb = (unsigned short*)((char*)d_out + (4u << 20));

    char* ws = (char*)d_ws;
    const bool big = ws_size >= (48ull << 20);

    // K0: T1 + T2 + cvt(x->xb), fused (2048+2048+2048 blocks)
    prep_stage1<<<6144, 256, 0, stream>>>(fc1_c1, fc1_c2, T1,
                                          fc2_c1, fc2_c2, T2, x, xb);

    if (big) {
        // ws: W1 [0,8M), W2 [8,16M), h bf16 [16,48M)
        unsigned short* W1 = (unsigned short*)ws;
        unsigned short* W2 = (unsigned short*)(ws + (8u << 20));
        unsigned short* h  = (unsigned short*)(ws + (16u << 20));

        // K1: both weight matrices (2048 + 1024 blocks)
        build_W_both<<<3072, 256, 0, stream>>>(fc1_c0, T1, W1,
                                               fc2_c0, T2, W2);
        // K2: GEMM1 [4096,1024]x[1024,4096]^T + bias + GELU -> h (bf16)
        //     R0 config: 128x128 tile, grid 32x32, 512 threads.
        gemm_pc<128, 128, 1024, true, false, false>
            <<<dim3(32, 32), 512, 0, stream>>>(xb, W1, fc1_b, h, 4096);
        // K3: GEMM2 [4096,4096]x[4096,1024]^T + bias -> d_out (f32)
        //     R0 config: 128x64 tile, grid 16x32.
        gemm_pc<128, 64, 4096, false, false, true>
            <<<dim3(16, 32), 512, 0, stream>>>(h, W2, fc2_b, d_out, 1024);
    } else {
        // Fallback (ws >= 40 MB): W [0,8M) reused per layer, h [8,40M).
        unsigned short* W = (unsigned short*)ws;
        unsigned short* h = (unsigned short*)(ws + (8u << 20));

        build_W<8, 16, 8, 16, 16, 16><<<2048, 256, 0, stream>>>(fc1_c0, T1, W);
        gemm_pc<128, 128, 1024, true, false, false>
            <<<dim3(32, 32), 512, 0, stream>>>(xb, W, fc1_b, h, 4096);
        build_W<16, 16, 16, 8, 16, 8><<<1024, 256, 0, stream>>>(fc2_c0, T2, W);
        gemm_pc<128, 64, 4096, false, false, true>
            <<<dim3(16, 32), 512, 0, stream>>>(h, W, fc2_b, d_out, 1024);
    }
}